// Round 1
// baseline (814.698 us; speedup 1.0000x reference)
//
#include <hip/hip_runtime.h>
#include <math.h>

#define N_PART 4096
#define N_T    400
#define N_O    9
#define LOG2PI_F 1.8378770664093453f

// One thread per particle. All 4x4 / 3x3 matrix work scalarized into registers.
// Regime 1 uses Woodbury with diagonal G (disjoint column supports of L1);
// regime 2 uses Sherman-Morrison rank-1. No Cholesky, no LDS.
__global__ __launch_bounds__(64)
void imm_kf_kernel(const float* __restrict__ y,
                   const float* __restrict__ B1s1,
                   const float* __restrict__ B1s2,
                   const float* __restrict__ l1f,
                   const float* __restrict__ l2f,
                   const float* __restrict__ log_q,
                   const float* __restrict__ log_r,
                   const float* __restrict__ gip,
                   const float* __restrict__ gcp,
                   float* __restrict__ out_probs,   // [N,NT,2]
                   float* __restrict__ out_ypred,   // [N,NT,9]
                   float* __restrict__ ll_ws)
{
    const int n = blockIdx.x * 64 + threadIdx.x;
    if (n >= N_PART) return;

    // ---- uniform constants (compiler should keep these scalar) ----
    float B1[3][3];
#pragma unroll
    for (int i = 0; i < 3; ++i)
#pragma unroll
        for (int j = 0; j < 3; ++j) B1[i][j] = B1s1[i*3+j];
    const float b2 = B1s2[0];

    float lam1[9], lam2[9];
    lam1[0] = 1.0f; lam1[1] = l1f[0]; lam1[2] = l1f[1];
    lam1[3] = 1.0f; lam1[4] = l1f[2]; lam1[5] = l1f[3];
    lam1[6] = 1.0f; lam1[7] = l1f[4]; lam1[8] = l1f[5];
    lam2[0] = 1.0f;
#pragma unroll
    for (int o = 1; o < 9; ++o) lam2[o] = l2f[o-1];

    float q[4];
#pragma unroll
    for (int i = 0; i < 4; ++i) q[i] = expf(log_q[i]);

    float ri[9], a1[9], u2[9];
    float logdetR = 0.0f;
    float g[3] = {0.f,0.f,0.f}, gh[3] = {0.f,0.f,0.f};
    float g2 = 0.0f, gh2 = 0.0f;
#pragma unroll
    for (int o = 0; o < 9; ++o) {
        float rr  = expf(log_r[o]);
        float rj  = rr + 1e-6f;           // R + JITTER (jitter folded into R~)
        float riv = 1.0f / rj;
        ri[o] = riv;
        logdetR += logf(rj);
        a1[o] = lam1[o] * riv;
        u2[o] = lam2[o] * riv;
        const int c = o / 3;
        g[c]  += lam1[o] * a1[o];         // U^T R~^-1 U (diagonal)
        gh[c] += a1[o] * a1[o] * rr;      // for K R K^T
        g2  += lam2[o] * u2[o];
        gh2 += u2[o] * u2[o] * rr;
    }
    const float gi  = gip[0];
    const float gc0 = gcp[0], gc1 = gcp[1], gc2 = gcp[2];
    const float llconst = 9.0f * LOG2PI_F + logdetR;

    // ---- state ----
    float P[4][4];
#pragma unroll
    for (int i = 0; i < 4; ++i)
#pragma unroll
        for (int j = 0; j < 4; ++j) P[i][j] = (i == j) ? 1000.0f : 0.0f;
    float eta[4] = {0.f,0.f,0.f,0.f};
    float pr1 = 0.99f, pr2 = 0.01f;
    float llacc = 0.0f;

    const float* yb = y + (size_t)n * (N_T * N_O);
    float* pb = out_probs + (size_t)n * (N_T * 2);
    float* yp = out_ypred + (size_t)n * (N_T * N_O);

    float ycur[9];
#pragma unroll
    for (int o = 0; o < 9; ++o) ycur[o] = yb[o];

    for (int t = 0; t < N_T; ++t) {
        // software prefetch next timestep's observations (one iter of latency hiding)
        float ynx[9];
        const int tn = (t + 1 < N_T) ? (t + 1) : t;
        const float* ybn = yb + tn * N_O;
#pragma unroll
        for (int o = 0; o < 9; ++o) ynx[o] = ybn[o];

        // transition prob from carry eta
        const float xg  = gi + eta[0]*gc0 + eta[1]*gc1 + eta[2]*gc2;
        const float p11 = 1.0f / (1.0f + expf(-xg));

        // ---- prediction: ep = B eta ; Pp = B P B^T + Q (block-diagonal B) ----
        float ep[4];
#pragma unroll
        for (int i = 0; i < 3; ++i)
            ep[i] = B1[i][0]*eta[0] + B1[i][1]*eta[1] + B1[i][2]*eta[2];
        ep[3] = b2 * eta[3];

        float C[3][3];
#pragma unroll
        for (int i = 0; i < 3; ++i)
#pragma unroll
            for (int k = 0; k < 3; ++k)
                C[i][k] = B1[i][0]*P[0][k] + B1[i][1]*P[1][k] + B1[i][2]*P[2][k];

        float Pp[4][4];
#pragma unroll
        for (int i = 0; i < 3; ++i)
#pragma unroll
            for (int j = i; j < 3; ++j) {
                float s = C[i][0]*B1[j][0] + C[i][1]*B1[j][1] + C[i][2]*B1[j][2];
                if (i == j) s += q[i];
                Pp[i][j] = s; Pp[j][i] = s;
            }
#pragma unroll
        for (int i = 0; i < 3; ++i) {
            float s = b2 * (B1[i][0]*P[0][3] + B1[i][1]*P[1][3] + B1[i][2]*P[2][3]);
            Pp[i][3] = s; Pp[3][i] = s;
        }
        Pp[3][3] = b2*b2*P[3][3] + q[3];

        // ---- regime 1 (Woodbury, G diagonal) ----
        float v1[9];
#pragma unroll
        for (int o = 0; o < 9; ++o) v1[o] = ycur[o] - lam1[o]*ep[o/3];
        float vRv1 = 0.0f;
#pragma unroll
        for (int o = 0; o < 9; ++o) vRv1 += v1[o]*v1[o]*ri[o];
        const float b0  = a1[0]*v1[0] + a1[1]*v1[1] + a1[2]*v1[2];
        const float b1  = a1[3]*v1[3] + a1[4]*v1[4] + a1[5]*v1[5];
        const float bb2 = a1[6]*v1[6] + a1[7]*v1[7] + a1[8]*v1[8];

        // M = I + S*diag(g), S = Pp[0:3][0:3]
        const float M00 = 1.0f + Pp[0][0]*g[0], M01 = Pp[0][1]*g[1], M02 = Pp[0][2]*g[2];
        const float M10 = Pp[1][0]*g[0], M11 = 1.0f + Pp[1][1]*g[1], M12 = Pp[1][2]*g[2];
        const float M20 = Pp[2][0]*g[0], M21 = Pp[2][1]*g[1], M22 = 1.0f + Pp[2][2]*g[2];

        const float co00 = M11*M22 - M12*M21;
        const float co01 = M12*M20 - M10*M22;
        const float co02 = M10*M21 - M11*M20;
        const float det  = M00*co00 + M01*co01 + M02*co02;   // > 1 always (S,G PD)
        const float idet = 1.0f / det;
        const float Mi00 = co00*idet;
        const float Mi01 = (M02*M21 - M01*M22)*idet;
        const float Mi02 = (M01*M12 - M02*M11)*idet;
        const float Mi10 = co01*idet;
        const float Mi11 = (M00*M22 - M02*M20)*idet;
        const float Mi12 = (M02*M10 - M00*M12)*idet;
        const float Mi20 = co02*idet;
        const float Mi21 = (M01*M20 - M00*M21)*idet;
        const float Mi22 = (M00*M11 - M01*M10)*idet;

        // qf1 = v R~^-1 v - b^T Minv (S b)
        const float sb0 = Pp[0][0]*b0 + Pp[0][1]*b1 + Pp[0][2]*bb2;
        const float sb1 = Pp[1][0]*b0 + Pp[1][1]*b1 + Pp[1][2]*bb2;
        const float sb2 = Pp[2][0]*b0 + Pp[2][1]*b1 + Pp[2][2]*bb2;
        const float ms0 = Mi00*sb0 + Mi01*sb1 + Mi02*sb2;
        const float ms1 = Mi10*sb0 + Mi11*sb1 + Mi12*sb2;
        const float ms2 = Mi20*sb0 + Mi21*sb1 + Mi22*sb2;
        const float qf1 = vRv1 - (b0*ms0 + b1*ms1 + bb2*ms2);
        const float ll1 = -0.5f*(llconst + logf(det) + qf1);

        // J = Pc Minv^T : J[l][c] = sum_k Pp[l][k]*Minv[c][k]
        float J[4][3];
#pragma unroll
        for (int l = 0; l < 4; ++l) {
            J[l][0] = Pp[l][0]*Mi00 + Pp[l][1]*Mi01 + Pp[l][2]*Mi02;
            J[l][1] = Pp[l][0]*Mi10 + Pp[l][1]*Mi11 + Pp[l][2]*Mi12;
            J[l][2] = Pp[l][0]*Mi20 + Pp[l][1]*Mi21 + Pp[l][2]*Mi22;
        }
        float eta1[4];
#pragma unroll
        for (int l = 0; l < 4; ++l)
            eta1[l] = ep[l] + J[l][0]*b0 + J[l][1]*b1 + J[l][2]*bb2;

        float Jg[4][3];
#pragma unroll
        for (int l = 0; l < 4; ++l) {
            Jg[l][0] = J[l][0]*g[0];
            Jg[l][1] = J[l][1]*g[1];
            Jg[l][2] = J[l][2]*g[2];
        }
        // Z[i][j] = (Jg Pc^T)[i][j]; note Z[:,0:3] == Jg S by symmetry of Pp
        float Z[4][4];
#pragma unroll
        for (int i = 0; i < 4; ++i)
#pragma unroll
            for (int j = 0; j < 4; ++j)
                Z[i][j] = Jg[i][0]*Pp[j][0] + Jg[i][1]*Pp[j][1] + Jg[i][2]*Pp[j][2];

        // Joseph form: P1 = Pp - Z - Z^T + Jg S Jg^T + J Ghat J^T
        float P1[4][4];
#pragma unroll
        for (int i = 0; i < 4; ++i)
#pragma unroll
            for (int j = i; j < 4; ++j) {
                const float w  = Z[i][0]*Jg[j][0] + Z[i][1]*Jg[j][1] + Z[i][2]*Jg[j][2];
                const float yv = J[i][0]*gh[0]*J[j][0] + J[i][1]*gh[1]*J[j][1] + J[i][2]*gh[2]*J[j][2];
                const float val = Pp[i][j] - Z[i][j] - Z[j][i] + w + yv;
                P1[i][j] = val; P1[j][i] = val;
            }

        // ---- regime 2 (rank-1 Sherman-Morrison) ----
        float v2[9];
#pragma unroll
        for (int o = 0; o < 9; ++o) v2[o] = ycur[o] - lam2[o]*ep[3];
        float vRv2 = 0.0f, bv2 = 0.0f;
#pragma unroll
        for (int o = 0; o < 9; ++o) { vRv2 += v2[o]*v2[o]*ri[o]; bv2 += u2[o]*v2[o]; }
        const float s22 = Pp[3][3];
        const float d2  = 1.0f + s22*g2;
        const float id2 = 1.0f / d2;
        const float qf2 = vRv2 - s22*id2*bv2*bv2;
        const float ll2 = -0.5f*(llconst + logf(d2) + qf2);
        const float kv  = bv2 * id2;
        const float p3v[4] = {Pp[0][3], Pp[1][3], Pp[2][3], Pp[3][3]};
        float eta2[4];
#pragma unroll
        for (int l = 0; l < 4; ++l) eta2[l] = ep[l] + p3v[l]*kv;
        const float aa   = g2*id2;
        const float beta = 2.0f*aa - aa*aa*s22 - gh2*id2*id2;
        float P2[4][4];
#pragma unroll
        for (int i = 0; i < 4; ++i)
#pragma unroll
            for (int j = i; j < 4; ++j) {
                const float val = Pp[i][j] - beta*p3v[i]*p3v[j];
                P2[i][j] = val; P2[j][i] = val;
            }

        // ---- IMM mixing ----
        const float e1 = expf(ll1), e2 = expf(ll2);
        const float num1 = e1 * (pr1 * p11);
        const float num2 = e2 * (pr1 * (1.0f - p11) + pr2);
        const float marg = num1 + num2 + 1e-9f;
        const float im   = 1.0f / marg;
        const float w1   = num1 * im;
        const float w2m  = num2 * im;
        llacc += logf(marg);

        float etat[4];
#pragma unroll
        for (int l = 0; l < 4; ++l) etat[l] = w1*eta1[l] + w2m*eta2[l];
#pragma unroll
        for (int i = 0; i < 4; ++i)
#pragma unroll
            for (int j = i; j < 4; ++j) {
                const float dd1 = (eta1[i]-etat[i])*(eta1[j]-etat[j]);
                const float dd2 = (eta2[i]-etat[i])*(eta2[j]-etat[j]);
                const float val = w1*(P1[i][j]+dd1) + w2m*(P2[i][j]+dd2);
                P[i][j] = val; P[j][i] = val;   // exactly symmetric == 0.5(Pt+Pt^T)
            }
#pragma unroll
        for (int l = 0; l < 4; ++l) eta[l] = etat[l];
        pr1 = w1; pr2 = w2m;

        // ---- outputs ----
        pb[t*2+0] = w1; pb[t*2+1] = w2m;
#pragma unroll
        for (int o = 0; o < 9; ++o)
            yp[t*N_O+o] = w1*lam1[o]*etat[o/3] + w2m*lam2[o]*etat[3];

#pragma unroll
        for (int o = 0; o < 9; ++o) ycur[o] = ynx[o];
    }

    // ---- wave-level ll reduction, one atomic per block (block == 1 wave) ----
#pragma unroll
    for (int off = 32; off > 0; off >>= 1)
        llacc += __shfl_down(llacc, off, 64);
    if (threadIdx.x == 0) atomicAdd(ll_ws, llacc);
}

__global__ void finalize_kernel(const float* __restrict__ ll_ws, float* __restrict__ out0)
{
    out0[0] = -ll_ws[0];
}

extern "C" void kernel_launch(void* const* d_in, const int* in_sizes, int n_in,
                              void* d_out, int out_size, void* d_ws, size_t ws_size,
                              hipStream_t stream)
{
    const float* y    = (const float*)d_in[0];
    const float* B1s1 = (const float*)d_in[1];
    const float* B1s2 = (const float*)d_in[2];
    const float* l1f  = (const float*)d_in[3];
    const float* l2f  = (const float*)d_in[4];
    const float* lq   = (const float*)d_in[5];
    const float* lr   = (const float*)d_in[6];
    const float* gi   = (const float*)d_in[7];
    const float* gc   = (const float*)d_in[8];

    float* out   = (float*)d_out;
    float* probs = out + 1;                                    // [N,NT,2]
    float* ypred = out + 1 + (size_t)N_PART * N_T * 2;         // [N,NT,9]
    float* ws    = (float*)d_ws;

    hipMemsetAsync(ws, 0, sizeof(float), stream);              // ws is re-poisoned each launch
    imm_kf_kernel<<<N_PART/64, 64, 0, stream>>>(y, B1s1, B1s2, l1f, l2f,
                                                lq, lr, gi, gc, probs, ypred, ws);
    finalize_kernel<<<1, 1, 0, stream>>>(ws, out);
}